// Round 1
// baseline (2288.106 us; speedup 1.0000x reference)
//
#include <hip/hip_runtime.h>
#include <hip/hip_bf16.h>
#include <cstdint>

#define B_  64
#define T_  32
#define E_  300
#define EP  320      // padded K for the x-precompute GEMM
#define H_  1024
#define G4  4096     // 4*H

typedef __attribute__((ext_vector_type(8))) short bf16x8;
typedef __attribute__((ext_vector_type(4))) float f32x4;
typedef unsigned short ushort_t;

__device__ __forceinline__ bf16x8 load_b8(const ushort_t* p) {
    union { uint4 u; bf16x8 v; } c;
    c.u = *reinterpret_cast<const uint4*>(p);
    return c.v;
}

__device__ __forceinline__ ushort_t f2bf(float x) {
    union { float f; uint32_t u; } c; c.f = x;
    uint32_t r = c.u + 0x7fffu + ((c.u >> 16) & 1u);   // RNE
    return (ushort_t)(r >> 16);
}

__device__ __forceinline__ float sigm(float x) { return 1.0f / (1.0f + __expf(-x)); }

// ---------------- prep kernels ----------------

__global__ void convert_f32_bf16(const float* __restrict__ src, ushort_t* __restrict__ dst, int n) {
    int i = blockIdx.x * blockDim.x + threadIdx.x;
    int stride = gridDim.x * blockDim.x;
    for (; i < n; i += stride) dst[i] = f2bf(src[i]);
}

// W_ih1 [4096,300] fp32 -> [4096,320] bf16 zero-padded
__global__ void pad_convert_wih1(const float* __restrict__ src, ushort_t* __restrict__ dst) {
    int i = blockIdx.x * blockDim.x + threadIdx.x;
    int stride = gridDim.x * blockDim.x;
    const int n = G4 * EP;
    for (; i < n; i += stride) {
        int r = i / EP, c = i - r * EP;
        dst[i] = (c < E_) ? f2bf(src[r * E_ + c]) : (ushort_t)0;
    }
}

// gather embeddings -> Xp [2048,320] bf16 zero-padded
__global__ void gather_embed(const int* __restrict__ q, const float* __restrict__ table,
                             ushort_t* __restrict__ Xp) {
    int i = blockIdx.x * blockDim.x + threadIdx.x;
    int stride = gridDim.x * blockDim.x;
    const int n = B_ * T_ * EP;
    for (; i < n; i += stride) {
        int r = i / EP, c = i - r * EP;
        Xp[i] = (c < E_) ? f2bf(table[q[r] * E_ + c]) : (ushort_t)0;
    }
}

__global__ void prep_bias_state(const float* __restrict__ b_ih1, const float* __restrict__ b_hh1,
                                const float* __restrict__ b_ih2, const float* __restrict__ b_hh2,
                                float* __restrict__ bias1, float* __restrict__ bias2,
                                float* __restrict__ h1f, float* __restrict__ c1f,
                                float* __restrict__ h2f, float* __restrict__ c2f,
                                ushort_t* __restrict__ h1bA, ushort_t* __restrict__ h1bB,
                                ushort_t* __restrict__ h2bA, ushort_t* __restrict__ h2bB) {
    int i = blockIdx.x * blockDim.x + threadIdx.x;  // exactly B_*H_ threads
    if (i < G4) { bias1[i] = b_ih1[i] + b_hh1[i]; bias2[i] = b_ih2[i] + b_hh2[i]; }
    if (i < B_ * H_) {
        h1f[i] = 0.f; c1f[i] = 0.f; h2f[i] = 0.f; c2f[i] = 0.f;
        h1bA[i] = 0; h1bB[i] = 0; h2bA[i] = 0; h2bB[i] = 0;
    }
}

// ---------------- x-part precompute GEMM ----------------
// xg[2048,4096] = Xp @ Wih1p^T + (b_ih1+b_hh1)
__launch_bounds__(256)
__global__ void xgemm(const ushort_t* __restrict__ Xp, const ushort_t* __restrict__ Wp,
                      const float* __restrict__ bias1, float* __restrict__ xg) {
    int mblk = blockIdx.x, nblk = blockIdx.y;
    int wave = threadIdx.x >> 6, lane = threadIdx.x & 63;
    int lm = lane & 15, lq = lane >> 4;
    int m0 = mblk * 64 + wave * 16;
    f32x4 acc[4];
    #pragma unroll
    for (int g = 0; g < 4; ++g) {
        float bv = bias1[nblk * 64 + g * 16 + lm];
        acc[g] = (f32x4){bv, bv, bv, bv};
    }
    for (int k0 = 0; k0 < EP; k0 += 32) {
        bf16x8 a = load_b8(Xp + (m0 + lm) * EP + k0 + lq * 8);
        #pragma unroll
        for (int g = 0; g < 4; ++g) {
            bf16x8 b = load_b8(Wp + (nblk * 64 + g * 16 + lm) * EP + k0 + lq * 8);
            acc[g] = __builtin_amdgcn_mfma_f32_16x16x32_bf16(a, b, acc[g], 0, 0, 0);
        }
    }
    #pragma unroll
    for (int g = 0; g < 4; ++g)
        #pragma unroll
        for (int r = 0; r < 4; ++r) {
            int m = m0 + lq * 4 + r;
            int n = nblk * 64 + g * 16 + lm;
            xg[m * G4 + n] = acc[g][r];
        }
}

// ---------------- recurrent step kernels ----------------
// grid 64 blocks (hidden slices of 16), block 256 = 4 waves (M-tiles of 16 batch rows)

__launch_bounds__(256)
__global__ void lstm_step1(const ushort_t* __restrict__ Whh1,
                           const ushort_t* __restrict__ h1b_prev,
                           const float* __restrict__ xg,
                           const int* __restrict__ qlen,
                           float* __restrict__ h1f, float* __restrict__ c1f,
                           ushort_t* __restrict__ h1b_next, int t) {
    int js = blockIdx.x;
    int wave = threadIdx.x >> 6, lane = threadIdx.x & 63;
    int lm = lane & 15, lq = lane >> 4;
    int m0 = wave * 16;

    f32x4 acc[4];
    #pragma unroll
    for (int g = 0; g < 4; ++g)
        #pragma unroll
        for (int r = 0; r < 4; ++r) {
            int b = m0 + lq * 4 + r;
            acc[g][r] = xg[(b * T_ + t) * G4 + g * H_ + js * 16 + lm];
        }

    for (int k0 = 0; k0 < H_; k0 += 32) {
        bf16x8 a = load_b8(h1b_prev + (m0 + lm) * H_ + k0 + lq * 8);
        #pragma unroll
        for (int g = 0; g < 4; ++g) {
            bf16x8 bb = load_b8(Whh1 + (g * H_ + js * 16 + lm) * H_ + k0 + lq * 8);
            acc[g] = __builtin_amdgcn_mfma_f32_16x16x32_bf16(a, bb, acc[g], 0, 0, 0);
        }
    }

    #pragma unroll
    for (int r = 0; r < 4; ++r) {
        int b = m0 + lq * 4 + r;
        int j = js * 16 + lm;
        ushort_t hb_out;
        if (t < qlen[b]) {
            float iv = sigm(acc[0][r]);
            float fv = sigm(acc[1][r]);
            float gv = tanhf(acc[2][r]);
            float ov = sigm(acc[3][r]);
            float cn = fv * c1f[b * H_ + j] + iv * gv;
            float hn = ov * tanhf(cn);
            c1f[b * H_ + j] = cn;
            h1f[b * H_ + j] = hn;
            hb_out = f2bf(hn);
        } else {
            hb_out = h1b_prev[b * H_ + j];
        }
        h1b_next[b * H_ + j] = hb_out;
    }
}

__launch_bounds__(256)
__global__ void lstm_step2(const ushort_t* __restrict__ Wih2, const ushort_t* __restrict__ Whh2,
                           const ushort_t* __restrict__ h1b_new, const ushort_t* __restrict__ h2b_prev,
                           const float* __restrict__ bias2, const int* __restrict__ qlen,
                           float* __restrict__ h2f, float* __restrict__ c2f,
                           ushort_t* __restrict__ h2b_next, int t) {
    int js = blockIdx.x;
    int wave = threadIdx.x >> 6, lane = threadIdx.x & 63;
    int lm = lane & 15, lq = lane >> 4;
    int m0 = wave * 16;

    f32x4 acc[4];
    #pragma unroll
    for (int g = 0; g < 4; ++g) {
        float bv = bias2[g * H_ + js * 16 + lm];
        acc[g] = (f32x4){bv, bv, bv, bv};
    }

    for (int k0 = 0; k0 < H_; k0 += 32) {
        bf16x8 a = load_b8(h1b_new + (m0 + lm) * H_ + k0 + lq * 8);
        #pragma unroll
        for (int g = 0; g < 4; ++g) {
            bf16x8 bb = load_b8(Wih2 + (g * H_ + js * 16 + lm) * H_ + k0 + lq * 8);
            acc[g] = __builtin_amdgcn_mfma_f32_16x16x32_bf16(a, bb, acc[g], 0, 0, 0);
        }
    }
    for (int k0 = 0; k0 < H_; k0 += 32) {
        bf16x8 a = load_b8(h2b_prev + (m0 + lm) * H_ + k0 + lq * 8);
        #pragma unroll
        for (int g = 0; g < 4; ++g) {
            bf16x8 bb = load_b8(Whh2 + (g * H_ + js * 16 + lm) * H_ + k0 + lq * 8);
            acc[g] = __builtin_amdgcn_mfma_f32_16x16x32_bf16(a, bb, acc[g], 0, 0, 0);
        }
    }

    #pragma unroll
    for (int r = 0; r < 4; ++r) {
        int b = m0 + lq * 4 + r;
        int j = js * 16 + lm;
        ushort_t hb_out;
        if (t < qlen[b]) {
            float iv = sigm(acc[0][r]);
            float fv = sigm(acc[1][r]);
            float gv = tanhf(acc[2][r]);
            float ov = sigm(acc[3][r]);
            float cn = fv * c2f[b * H_ + j] + iv * gv;
            float hn = ov * tanhf(cn);
            c2f[b * H_ + j] = cn;
            h2f[b * H_ + j] = hn;
            hb_out = f2bf(hn);
        } else {
            hb_out = h2b_prev[b * H_ + j];
        }
        h2b_next[b * H_ + j] = hb_out;
    }
}

// ---------------- output fan-out ----------------
__global__ void write_out(const float* __restrict__ h1f, const float* __restrict__ h2f,
                          const float* __restrict__ c1f, const float* __restrict__ c2f,
                          float* __restrict__ out) {
    const long long EQ = (long long)B_ * H_ * 784;      // 51,380,224
    const long long n4 = (EQ + 4LL * B_ * H_) / 4;      // 12,910,592
    long long i4 = (long long)blockIdx.x * blockDim.x + threadIdx.x;
    long long stride = (long long)gridDim.x * blockDim.x;
    for (; i4 < n4; i4 += stride) {
        long long f = i4 * 4;
        float4 v;
        if (f < EQ) {
            long long bh = f / 784;
            float val = h2f[bh];
            v = make_float4(val, val, val, val);
        } else {
            long long r = f - EQ;
            int which = (int)(r >> 16);
            int j = (int)(r & 65535);
            const float* src = (which == 0) ? h1f : (which == 1) ? h2f : (which == 2) ? c1f : c2f;
            v = *reinterpret_cast<const float4*>(src + j);
        }
        reinterpret_cast<float4*>(out)[i4] = v;
    }
}

// ---------------- launch ----------------
extern "C" void kernel_launch(void* const* d_in, const int* in_sizes, int n_in,
                              void* d_out, int out_size, void* d_ws, size_t ws_size,
                              hipStream_t stream) {
    const int*   questions = (const int*)d_in[0];
    const int*   qlen      = (const int*)d_in[1];
    const float* embed     = (const float*)d_in[2];
    const float* W_ih1     = (const float*)d_in[3];
    const float* W_hh1     = (const float*)d_in[4];
    const float* b_ih1     = (const float*)d_in[5];
    const float* b_hh1     = (const float*)d_in[6];
    const float* W_ih2     = (const float*)d_in[7];
    const float* W_hh2     = (const float*)d_in[8];
    const float* b_ih2     = (const float*)d_in[9];
    const float* b_hh2     = (const float*)d_in[10];
    float* out = (float*)d_out;

    char* w = (char*)d_ws;
    float*    xg    = (float*)(w + 0);                      // 33,554,432 B
    ushort_t* Whh1b = (ushort_t*)(w + 33554432);            //  8,388,608 B
    ushort_t* Wih2b = (ushort_t*)(w + 41943040);            //  8,388,608 B
    ushort_t* Whh2b = (ushort_t*)(w + 50331648);            //  8,388,608 B
    ushort_t* Wih1p = (ushort_t*)(w + 58720256);            //  2,621,440 B
    ushort_t* Xp    = (ushort_t*)(w + 61341696);            //  1,310,720 B
    float*    bias1 = (float*)(w + 62652416);               //     16,384 B
    float*    bias2 = (float*)(w + 62668800);               //     16,384 B
    float*    h1f   = (float*)(w + 62685184);               //    262,144 B
    float*    c1f   = (float*)(w + 62947328);
    float*    h2f   = (float*)(w + 63209472);
    float*    c2f   = (float*)(w + 63471616);
    ushort_t* h1bA  = (ushort_t*)(w + 63733760);            //    131,072 B
    ushort_t* h1bB  = (ushort_t*)(w + 63864832);
    ushort_t* h2bA  = (ushort_t*)(w + 63995904);
    ushort_t* h2bB  = (ushort_t*)(w + 64126976);            // end 64,258,048 B

    convert_f32_bf16<<<2048, 256, 0, stream>>>(W_hh1, Whh1b, G4 * H_);
    convert_f32_bf16<<<2048, 256, 0, stream>>>(W_ih2, Wih2b, G4 * H_);
    convert_f32_bf16<<<2048, 256, 0, stream>>>(W_hh2, Whh2b, G4 * H_);
    pad_convert_wih1<<<2048, 256, 0, stream>>>(W_ih1, Wih1p);
    gather_embed<<<1280, 256, 0, stream>>>(questions, embed, Xp);
    prep_bias_state<<<256, 256, 0, stream>>>(b_ih1, b_hh1, b_ih2, b_hh2, bias1, bias2,
                                             h1f, c1f, h2f, c2f, h1bA, h1bB, h2bA, h2bB);
    xgemm<<<dim3(32, 64), 256, 0, stream>>>(Xp, Wih1p, bias1, xg);

    ushort_t* h1prev = h1bA; ushort_t* h1next = h1bB;
    ushort_t* h2prev = h2bA; ushort_t* h2next = h2bB;
    for (int t = 0; t < T_; ++t) {
        lstm_step1<<<64, 256, 0, stream>>>(Whh1b, h1prev, xg, qlen, h1f, c1f, h1next, t);
        lstm_step2<<<64, 256, 0, stream>>>(Wih2b, Whh2b, h1next, h2prev, bias2, qlen,
                                           h2f, c2f, h2next, t);
        ushort_t* tmp;
        tmp = h1prev; h1prev = h1next; h1next = tmp;
        tmp = h2prev; h2prev = h2next; h2next = tmp;
    }

    write_out<<<4096, 256, 0, stream>>>(h1f, h2f, c1f, c2f, out);
}

// Round 2
// 1118.425 us; speedup vs baseline: 2.0458x; 2.0458x over previous
//
#include <hip/hip_runtime.h>
#include <hip/hip_bf16.h>
#include <cstdint>

#define B_  64
#define T_  32
#define E_  300
#define EP  320      // padded K for the x-precompute GEMM
#define H_  1024
#define G4  4096     // 4*H
#define NBLK 192     // persistent blocks: 64 L1 + 64 I2 + 64 H2
#define NSS  34      // supersteps (3-stage pipeline over 32 timesteps)

typedef __attribute__((ext_vector_type(8))) short bf16x8;
typedef __attribute__((ext_vector_type(4))) float f32x4;
typedef unsigned short ushort_t;

__device__ __forceinline__ bf16x8 load_b8(const ushort_t* p) {
    union { uint4 u; bf16x8 v; } c;
    c.u = *reinterpret_cast<const uint4*>(p);
    return c.v;
}

__device__ __forceinline__ ushort_t f2bf(float x) {
    union { float f; uint32_t u; } c; c.f = x;
    uint32_t r = c.u + 0x7fffu + ((c.u >> 16) & 1u);   // RNE
    return (ushort_t)(r >> 16);
}

__device__ __forceinline__ float sigm(float x) { return 1.0f / (1.0f + __expf(-x)); }

// ---------------- prep kernels ----------------

// W_ih1 [4096,300] fp32 -> [4096,320] bf16 zero-padded
__global__ void pad_convert_wih1(const float* __restrict__ src, ushort_t* __restrict__ dst) {
    int i = blockIdx.x * blockDim.x + threadIdx.x;
    int stride = gridDim.x * blockDim.x;
    const int n = G4 * EP;
    for (; i < n; i += stride) {
        int r = i / EP, c = i - r * EP;
        dst[i] = (c < E_) ? f2bf(src[r * E_ + c]) : (ushort_t)0;
    }
}

// gather embeddings -> Xp [2048,320] bf16 zero-padded
__global__ void gather_embed(const int* __restrict__ q, const float* __restrict__ table,
                             ushort_t* __restrict__ Xp) {
    int i = blockIdx.x * blockDim.x + threadIdx.x;
    int stride = gridDim.x * blockDim.x;
    const int n = B_ * T_ * EP;
    for (; i < n; i += stride) {
        int r = i / EP, c = i - r * EP;
        Xp[i] = (c < E_) ? f2bf(table[q[r] * E_ + c]) : (ushort_t)0;
    }
}

// ---------------- x-part precompute GEMM ----------------
// xg[2048,4096] = Xp @ Wih1p^T + (b_ih1+b_hh1)
__launch_bounds__(256)
__global__ void xgemm(const ushort_t* __restrict__ Xp, const ushort_t* __restrict__ Wp,
                      const float* __restrict__ b_ih1, const float* __restrict__ b_hh1,
                      float* __restrict__ xg) {
    int mblk = blockIdx.x, nblk = blockIdx.y;
    int wave = threadIdx.x >> 6, lane = threadIdx.x & 63;
    int lm = lane & 15, lq = lane >> 4;
    int m0 = mblk * 64 + wave * 16;
    f32x4 acc[4];
    #pragma unroll
    for (int g = 0; g < 4; ++g) {
        int n = nblk * 64 + g * 16 + lm;
        float bv = b_ih1[n] + b_hh1[n];
        acc[g] = (f32x4){bv, bv, bv, bv};
    }
    for (int k0 = 0; k0 < EP; k0 += 32) {
        bf16x8 a = load_b8(Xp + (m0 + lm) * EP + k0 + lq * 8);
        #pragma unroll
        for (int g = 0; g < 4; ++g) {
            bf16x8 b = load_b8(Wp + (nblk * 64 + g * 16 + lm) * EP + k0 + lq * 8);
            acc[g] = __builtin_amdgcn_mfma_f32_16x16x32_bf16(a, b, acc[g], 0, 0, 0);
        }
    }
    #pragma unroll
    for (int g = 0; g < 4; ++g)
        #pragma unroll
        for (int r = 0; r < 4; ++r) {
            int m = m0 + lq * 4 + r;
            int n = nblk * 64 + g * 16 + lm;
            xg[(size_t)m * G4 + n] = acc[g][r];
        }
}

// ---------------- persistent recurrence kernel ----------------
// blocks 0-63: L1 (Whh1), 64-127: I2 (Wih2), 128-191: H2 (Whh2)
// LDS: 64 rows x 1024 k bf16, row stride padded to 1032 (16B-aligned)

__device__ __forceinline__ void gemm_k1024(const ushort_t* __restrict__ hvec,
                                           const ushort_t w[64][1032],
                                           int lm, int lq, int m0, f32x4 acc[4]) {
    #pragma unroll 8
    for (int k0 = 0; k0 < H_; k0 += 32) {
        bf16x8 a = load_b8(hvec + (m0 + lm) * H_ + k0 + lq * 8);
        #pragma unroll
        for (int g = 0; g < 4; ++g) {
            bf16x8 bb = load_b8(&w[g * 16 + lm][k0 + lq * 8]);
            acc[g] = __builtin_amdgcn_mfma_f32_16x16x32_bf16(a, bb, acc[g], 0, 0, 0);
        }
    }
}

__global__ __launch_bounds__(256) void lstm_persist(
    const float* __restrict__ Whh1, const float* __restrict__ Wih2,
    const float* __restrict__ Whh2,
    const float* __restrict__ b_ih2, const float* __restrict__ b_hh2,
    const float* __restrict__ xg, const int* __restrict__ qlen,
    ushort_t* __restrict__ h1b0, ushort_t* __restrict__ h1b1,
    ushort_t* __restrict__ h2b0, ushort_t* __restrict__ h2b1,
    float* __restrict__ Qb0, float* __restrict__ Qb1,
    float* __restrict__ h1f, float* __restrict__ c1f,
    float* __restrict__ h2f, float* __restrict__ c2f,
    int* __restrict__ ctr)
{
    __shared__ ushort_t ws[64][1032];   // 132,096 B

    const int blk  = blockIdx.x;
    const int role = blk >> 6;          // 0=L1, 1=I2, 2=H2
    const int js   = blk & 63;
    const int wave = threadIdx.x >> 6, lane = threadIdx.x & 63;
    const int lm = lane & 15, lq = lane >> 4;
    const int m0 = wave * 16;

    // ---- stage weight slice fp32 -> bf16 into LDS (once) ----
    const float* Wsrc = (role == 0) ? Whh1 : (role == 1) ? Wih2 : Whh2;
    for (int idx = threadIdx.x; idx < 64 * 256; idx += 256) {
        int r = idx >> 8, c4 = idx & 255;
        int grow = (r >> 4) * H_ + js * 16 + (r & 15);
        float4 v = reinterpret_cast<const float4*>(Wsrc + (size_t)grow * H_)[c4];
        uint2 pk;
        pk.x = (uint32_t)f2bf(v.x) | ((uint32_t)f2bf(v.y) << 16);
        pk.y = (uint32_t)f2bf(v.z) | ((uint32_t)f2bf(v.w) << 16);
        *reinterpret_cast<uint2*>(&ws[r][c4 * 4]) = pk;
    }
    __syncthreads();

    int q[4];
    #pragma unroll
    for (int r = 0; r < 4; ++r) q[r] = qlen[m0 + lq * 4 + r];

    float bi[4] = {0, 0, 0, 0};
    if (role == 1) {
        #pragma unroll
        for (int g = 0; g < 4; ++g) {
            int n = g * H_ + js * 16 + lm;
            bi[g] = b_ih2[n] + b_hh2[n];
        }
    }

    float    c_reg[4]  = {0.f, 0.f, 0.f, 0.f};
    ushort_t hb_reg[4] = {0, 0, 0, 0};

    for (int s = 0; s < NSS; ++s) {
        const int par = s & 1;

        if (role == 0 && s < 32) {
            const int t = s;
            const ushort_t* hp = par ? h1b1 : h1b0;   // h1(t-1)
            ushort_t*       hn = par ? h1b0 : h1b1;   // h1(t)
            f32x4 acc[4];
            #pragma unroll
            for (int g = 0; g < 4; ++g)
                #pragma unroll
                for (int r = 0; r < 4; ++r)
                    acc[g][r] = xg[((size_t)(m0 + lq * 4 + r) * T_ + t) * G4 + g * H_ + js * 16 + lm];
            gemm_k1024(hp, ws, lm, lq, m0, acc);
            #pragma unroll
            for (int r = 0; r < 4; ++r) {
                int b = m0 + lq * 4 + r, j = js * 16 + lm;
                if (t < q[r]) {
                    float iv = sigm(acc[0][r]);
                    float fv = sigm(acc[1][r]);
                    float gv = tanhf(acc[2][r]);
                    float ov = sigm(acc[3][r]);
                    float cn = fv * c_reg[r] + iv * gv;
                    float hv = ov * tanhf(cn);
                    c_reg[r] = cn;
                    h1f[b * H_ + j] = hv; c1f[b * H_ + j] = cn;
                    hb_reg[r] = f2bf(hv);
                }
                hn[b * H_ + j] = hb_reg[r];
            }
        } else if (role == 1 && s >= 1 && s <= 32) {
            // Q(t=s-1) = Wih2 . h1(t) + bias2
            const ushort_t* h1p = par ? h1b1 : h1b0;  // h1(s-1)
            float*          Qw  = par ? Qb1 : Qb0;    // parity s&1
            f32x4 acc[4];
            #pragma unroll
            for (int g = 0; g < 4; ++g) acc[g] = (f32x4){bi[g], bi[g], bi[g], bi[g]};
            gemm_k1024(h1p, ws, lm, lq, m0, acc);
            #pragma unroll
            for (int g = 0; g < 4; ++g)
                #pragma unroll
                for (int r = 0; r < 4; ++r)
                    Qw[(size_t)(m0 + lq * 4 + r) * G4 + g * H_ + js * 16 + lm] = acc[g][r];
        } else if (role == 2 && s >= 2) {
            const int t = s - 2;
            const ushort_t* h2p = par ? h2b1 : h2b0;  // h2(t-1), parity s&1
            ushort_t*       h2n = par ? h2b0 : h2b1;  // h2(t),   parity (s+1)&1
            const float*    Qr  = par ? Qb0 : Qb1;    // Q(t),    parity (s+1)&1
            f32x4 acc[4];
            #pragma unroll
            for (int g = 0; g < 4; ++g)
                #pragma unroll
                for (int r = 0; r < 4; ++r)
                    acc[g][r] = Qr[(size_t)(m0 + lq * 4 + r) * G4 + g * H_ + js * 16 + lm];
            gemm_k1024(h2p, ws, lm, lq, m0, acc);
            #pragma unroll
            for (int r = 0; r < 4; ++r) {
                int b = m0 + lq * 4 + r, j = js * 16 + lm;
                if (t < q[r]) {
                    float iv = sigm(acc[0][r]);
                    float fv = sigm(acc[1][r]);
                    float gv = tanhf(acc[2][r]);
                    float ov = sigm(acc[3][r]);
                    float cn = fv * c_reg[r] + iv * gv;
                    float hv = ov * tanhf(cn);
                    c_reg[r] = cn;
                    h2f[b * H_ + j] = hv; c2f[b * H_ + j] = cn;
                    hb_reg[r] = f2bf(hv);
                }
                h2n[b * H_ + j] = hb_reg[r];
            }
        }

        if (s < NSS - 1) {
            __syncthreads();
            if (threadIdx.x == 0) {
                __threadfence();
                __hip_atomic_fetch_add(&ctr[s], 1, __ATOMIC_RELEASE, __HIP_MEMORY_SCOPE_AGENT);
                while (__hip_atomic_load(&ctr[s], __ATOMIC_RELAXED, __HIP_MEMORY_SCOPE_AGENT) < NBLK)
                    __builtin_amdgcn_s_sleep(2);
                __threadfence();
            }
            __syncthreads();
        }
    }
}

// ---------------- output fan-out ----------------
__global__ void write_out(const float* __restrict__ h1f, const float* __restrict__ h2f,
                          const float* __restrict__ c1f, const float* __restrict__ c2f,
                          float* __restrict__ out) {
    const long long EQ = (long long)B_ * H_ * 784;      // 51,380,224
    const long long n4 = (EQ + 4LL * B_ * H_) / 4;      // 12,910,592
    long long i4 = (long long)blockIdx.x * blockDim.x + threadIdx.x;
    long long stride = (long long)gridDim.x * blockDim.x;
    for (; i4 < n4; i4 += stride) {
        long long f = i4 * 4;
        float4 v;
        if (f < EQ) {
            long long bh = f / 784;
            float val = h2f[bh];
            v = make_float4(val, val, val, val);
        } else {
            long long r = f - EQ;
            int which = (int)(r >> 16);
            int j = (int)(r & 65535);
            const float* src = (which == 0) ? h1f : (which == 1) ? h2f : (which == 2) ? c1f : c2f;
            v = *reinterpret_cast<const float4*>(src + j);
        }
        reinterpret_cast<float4*>(out)[i4] = v;
    }
}

// ---------------- launch ----------------
extern "C" void kernel_launch(void* const* d_in, const int* in_sizes, int n_in,
                              void* d_out, int out_size, void* d_ws, size_t ws_size,
                              hipStream_t stream) {
    const int*   questions = (const int*)d_in[0];
    const int*   qlen      = (const int*)d_in[1];
    const float* embed     = (const float*)d_in[2];
    const float* W_ih1     = (const float*)d_in[3];
    const float* W_hh1     = (const float*)d_in[4];
    const float* b_ih1     = (const float*)d_in[5];
    const float* b_hh1     = (const float*)d_in[6];
    const float* W_ih2     = (const float*)d_in[7];
    const float* W_hh2     = (const float*)d_in[8];
    const float* b_ih2     = (const float*)d_in[9];
    const float* b_hh2     = (const float*)d_in[10];
    float* out = (float*)d_out;

    char* w = (char*)d_ws;
    float*    xg    = (float*)(w + 0);                 // 33,554,432
    ushort_t* Wih1p = (ushort_t*)(w + 33554432);       //  2,621,440
    ushort_t* Xp    = (ushort_t*)(w + 36175872);       //  1,310,720
    float*    Qb0   = (float*)(w + 37486592);          //  1,048,576
    float*    Qb1   = (float*)(w + 38535168);          //  1,048,576
    float*    h1f   = (float*)(w + 39583744);          //    262,144
    float*    c1f   = (float*)(w + 39845888);
    float*    h2f   = (float*)(w + 40108032);
    float*    c2f   = (float*)(w + 40370176);
    ushort_t* h1b0  = (ushort_t*)(w + 40632320);       //    131,072
    ushort_t* h1b1  = (ushort_t*)(w + 40763392);
    ushort_t* h2b0  = (ushort_t*)(w + 40894464);
    ushort_t* h2b1  = (ushort_t*)(w + 41025536);
    int*      ctr   = (int*)(w + 41156608);            //        256  (end 41,156,864)

    // zero h1b0..h2b1 + ctr in one async memset (contiguous)
    hipMemsetAsync(w + 40632320, 0, 4 * 131072 + 256, stream);

    gather_embed<<<1280, 256, 0, stream>>>(questions, embed, Xp);
    pad_convert_wih1<<<2048, 256, 0, stream>>>(W_ih1, Wih1p);
    xgemm<<<dim3(32, 64), 256, 0, stream>>>(Xp, Wih1p, b_ih1, b_hh1, xg);

    lstm_persist<<<NBLK, 256, 0, stream>>>(W_hh1, W_ih2, W_hh2, b_ih2, b_hh2,
                                           xg, qlen,
                                           h1b0, h1b1, h2b0, h2b1, Qb0, Qb1,
                                           h1f, c1f, h2f, c2f, ctr);

    write_out<<<4096, 256, 0, stream>>>(h1f, h2f, c1f, c2f, out);
}

// Round 3
// 860.115 us; speedup vs baseline: 2.6602x; 1.3003x over previous
//
#include <hip/hip_runtime.h>
#include <hip/hip_bf16.h>
#include <cstdint>

#define B_  64
#define T_  32
#define E_  300
#define EP  320      // padded K for the x-precompute GEMM
#define H_  1024
#define G4  4096     // 4*H
#define NBLK 192     // persistent blocks: 64 L1 + 64 I2 + 64 H2
#define NSS  34      // supersteps (3-stage pipeline over 32 timesteps)

typedef __attribute__((ext_vector_type(8))) short bf16x8;
typedef __attribute__((ext_vector_type(4))) float f32x4;
typedef unsigned short ushort_t;

__device__ __forceinline__ bf16x8 load_b8(const ushort_t* p) {
    union { uint4 u; bf16x8 v; } c;
    c.u = *reinterpret_cast<const uint4*>(p);
    return c.v;
}

__device__ __forceinline__ ushort_t f2bf(float x) {
    union { float f; uint32_t u; } c; c.f = x;
    uint32_t r = c.u + 0x7fffu + ((c.u >> 16) & 1u);   // RNE
    return (ushort_t)(r >> 16);
}

__device__ __forceinline__ float sigm(float x) { return 1.0f / (1.0f + __expf(-x)); }

// relaxed agent-scope (cross-XCD coherent, fence-free) accessors -> global_* sc1
__device__ __forceinline__ uint64_t aload64(const uint64_t* p) {
    return __hip_atomic_load(p, __ATOMIC_RELAXED, __HIP_MEMORY_SCOPE_AGENT);
}
__device__ __forceinline__ void astore64(uint64_t* p, uint64_t v) {
    __hip_atomic_store(p, v, __ATOMIC_RELAXED, __HIP_MEMORY_SCOPE_AGENT);
}
__device__ __forceinline__ void astore16(ushort_t* p, ushort_t v) {
    __hip_atomic_store(p, v, __ATOMIC_RELAXED, __HIP_MEMORY_SCOPE_AGENT);
}
__device__ __forceinline__ uint64_t packf2(float a, float b) {
    union { float f[2]; uint64_t u; } c; c.f[0] = a; c.f[1] = b; return c.u;
}

// ---------------- prep kernels ----------------

// W_ih1 [4096,300] fp32 -> [4096,320] bf16 zero-padded
__global__ void pad_convert_wih1(const float* __restrict__ src, ushort_t* __restrict__ dst) {
    int i = blockIdx.x * blockDim.x + threadIdx.x;
    int stride = gridDim.x * blockDim.x;
    const int n = G4 * EP;
    for (; i < n; i += stride) {
        int r = i / EP, c = i - r * EP;
        dst[i] = (c < E_) ? f2bf(src[r * E_ + c]) : (ushort_t)0;
    }
}

// gather embeddings -> Xp [2048,320] bf16 zero-padded
__global__ void gather_embed(const int* __restrict__ q, const float* __restrict__ table,
                             ushort_t* __restrict__ Xp) {
    int i = blockIdx.x * blockDim.x + threadIdx.x;
    int stride = gridDim.x * blockDim.x;
    const int n = B_ * T_ * EP;
    for (; i < n; i += stride) {
        int r = i / EP, c = i - r * EP;
        Xp[i] = (c < E_) ? f2bf(table[q[r] * E_ + c]) : (ushort_t)0;
    }
}

// ---------------- x-part precompute GEMM ----------------
// xg[t][b][4H] = Xp @ Wih1p^T + (b_ih1+b_hh1)   (t-major for streaming in recurrence)
__launch_bounds__(256)
__global__ void xgemm(const ushort_t* __restrict__ Xp, const ushort_t* __restrict__ Wp,
                      const float* __restrict__ b_ih1, const float* __restrict__ b_hh1,
                      float* __restrict__ xg) {
    int mblk = blockIdx.x, nblk = blockIdx.y;
    int wave = threadIdx.x >> 6, lane = threadIdx.x & 63;
    int lm = lane & 15, lq = lane >> 4;
    int m0 = mblk * 64 + wave * 16;
    f32x4 acc[4];
    #pragma unroll
    for (int g = 0; g < 4; ++g) {
        int n = nblk * 64 + g * 16 + lm;
        float bv = b_ih1[n] + b_hh1[n];
        acc[g] = (f32x4){bv, bv, bv, bv};
    }
    for (int k0 = 0; k0 < EP; k0 += 32) {
        bf16x8 a = load_b8(Xp + (m0 + lm) * EP + k0 + lq * 8);
        #pragma unroll
        for (int g = 0; g < 4; ++g) {
            bf16x8 b = load_b8(Wp + (nblk * 64 + g * 16 + lm) * EP + k0 + lq * 8);
            acc[g] = __builtin_amdgcn_mfma_f32_16x16x32_bf16(a, b, acc[g], 0, 0, 0);
        }
    }
    #pragma unroll
    for (int g = 0; g < 4; ++g)
        #pragma unroll
        for (int r = 0; r < 4; ++r) {
            int m = m0 + lq * 4 + r;          // m = b*T + t
            int b = m >> 5, t = m & 31;
            int n = nblk * 64 + g * 16 + lm;
            xg[((size_t)t * B_ + b) * G4 + n] = acc[g][r];
        }
}

// ---------------- persistent recurrence kernel ----------------
// blocks 0-63: L1 (Whh1), 64-127: I2 (Wih2), 128-191: H2 (Whh2)

__device__ __forceinline__ void gemm_k1024(const uint64_t* __restrict__ hvec,  // bf16 h, u64 view
                                           const ushort_t w[64][1032],
                                           int lm, int lq, int m0, f32x4 acc[4]) {
    const uint64_t* hrow = hvec + (size_t)(m0 + lm) * (H_ / 4) + lq * 2;
    #pragma unroll 8
    for (int k0 = 0; k0 < H_; k0 += 32) {
        union { uint64_t u[2]; bf16x8 v; } a;
        a.u[0] = aload64(hrow + (k0 >> 2));
        a.u[1] = aload64(hrow + (k0 >> 2) + 1);
        #pragma unroll
        for (int g = 0; g < 4; ++g) {
            bf16x8 bb = load_b8(&w[g * 16 + lm][k0 + lq * 8]);
            acc[g] = __builtin_amdgcn_mfma_f32_16x16x32_bf16(a.v, bb, acc[g], 0, 0, 0);
        }
    }
}

__global__ __launch_bounds__(256) void lstm_persist(
    const float* __restrict__ Whh1, const float* __restrict__ Wih2,
    const float* __restrict__ Whh2,
    const float* __restrict__ b_ih2, const float* __restrict__ b_hh2,
    const float* __restrict__ xg, const int* __restrict__ qlen,
    ushort_t* __restrict__ h1b0, ushort_t* __restrict__ h1b1,
    ushort_t* __restrict__ h2b0, ushort_t* __restrict__ h2b1,
    float* __restrict__ Qb0, float* __restrict__ Qb1,
    float* __restrict__ h1f, float* __restrict__ c1f,
    float* __restrict__ h2f, float* __restrict__ c2f,
    int* __restrict__ ctr)
{
    __shared__ ushort_t ws[64][1032];   // 132,096 B

    const int blk  = blockIdx.x;
    const int role = blk >> 6;          // 0=L1, 1=I2, 2=H2
    const int js   = blk & 63;
    const int wave = threadIdx.x >> 6, lane = threadIdx.x & 63;
    const int lm = lane & 15, lq = lane >> 4;
    const int m0 = wave * 16;

    // ---- stage weight slice fp32 -> bf16 into LDS (once) ----
    const float* Wsrc = (role == 0) ? Whh1 : (role == 1) ? Wih2 : Whh2;
    for (int idx = threadIdx.x; idx < 64 * 256; idx += 256) {
        int r = idx >> 8, c4 = idx & 255;
        int grow = (r >> 4) * H_ + js * 16 + (r & 15);
        float4 v = reinterpret_cast<const float4*>(Wsrc + (size_t)grow * H_)[c4];
        uint2 pk;
        pk.x = (uint32_t)f2bf(v.x) | ((uint32_t)f2bf(v.y) << 16);
        pk.y = (uint32_t)f2bf(v.z) | ((uint32_t)f2bf(v.w) << 16);
        *reinterpret_cast<uint2*>(&ws[r][c4 * 4]) = pk;
    }
    __syncthreads();

    int q[4];
    #pragma unroll
    for (int r = 0; r < 4; ++r) q[r] = qlen[m0 + lq * 4 + r];

    float bi[4] = {0, 0, 0, 0};
    if (role == 1) {
        #pragma unroll
        for (int g = 0; g < 4; ++g) {
            int n = g * H_ + js * 16 + lm;
            bi[g] = b_ih2[n] + b_hh2[n];
        }
    }

    float    c_reg[4]  = {0.f, 0.f, 0.f, 0.f};
    float    h_reg[4]  = {0.f, 0.f, 0.f, 0.f};
    ushort_t hb_reg[4] = {0, 0, 0, 0};

    for (int s = 0; s < NSS; ++s) {
        const int par = s & 1;

        if (role == 0 && s < 32) {
            const int t = s;
            const ushort_t* hp = par ? h1b1 : h1b0;   // h1(t-1)
            ushort_t*       hn = par ? h1b0 : h1b1;   // h1(t)
            f32x4 acc[4];
            #pragma unroll
            for (int g = 0; g < 4; ++g)
                #pragma unroll
                for (int r = 0; r < 4; ++r)
                    acc[g][r] = xg[((size_t)t * B_ + (m0 + lq * 4 + r)) * G4 + g * H_ + js * 16 + lm];
            gemm_k1024((const uint64_t*)hp, ws, lm, lq, m0, acc);
            #pragma unroll
            for (int r = 0; r < 4; ++r) {
                int b = m0 + lq * 4 + r, j = js * 16 + lm;
                if (t < q[r]) {
                    float iv = sigm(acc[0][r]);
                    float fv = sigm(acc[1][r]);
                    float gv = tanhf(acc[2][r]);
                    float ov = sigm(acc[3][r]);
                    float cn = fv * c_reg[r] + iv * gv;
                    float hv = ov * tanhf(cn);
                    c_reg[r] = cn; h_reg[r] = hv;
                    hb_reg[r] = f2bf(hv);
                }
                astore16(&hn[b * H_ + j], hb_reg[r]);
            }
        } else if (role == 1 && s >= 1 && s <= 32) {
            // Q(t=s-1) = Wih2 . h1(t) + bias2   (Q layout: [b][j][4] gate-interleaved)
            const ushort_t* h1p = par ? h1b1 : h1b0;  // h1(s-1)
            float*          Qw  = par ? Qb1 : Qb0;    // parity s&1
            f32x4 acc[4];
            #pragma unroll
            for (int g = 0; g < 4; ++g) acc[g] = (f32x4){bi[g], bi[g], bi[g], bi[g]};
            gemm_k1024((const uint64_t*)h1p, ws, lm, lq, m0, acc);
            uint64_t* Qw64 = (uint64_t*)Qw;
            #pragma unroll
            for (int r = 0; r < 4; ++r) {
                int b = m0 + lq * 4 + r, j = js * 16 + lm;
                size_t base = ((size_t)b * H_ + j) * 2;
                astore64(Qw64 + base,     packf2(acc[0][r], acc[1][r]));
                astore64(Qw64 + base + 1, packf2(acc[2][r], acc[3][r]));
            }
        } else if (role == 2 && s >= 2) {
            const int t = s - 2;
            const ushort_t* h2p = par ? h2b1 : h2b0;  // h2(t-1), parity s&1
            ushort_t*       h2n = par ? h2b0 : h2b1;  // h2(t),   parity (s+1)&1
            const float*    Qr  = par ? Qb0 : Qb1;    // Q(t),    parity (s+1)&1
            f32x4 acc[4];
            const uint64_t* Qr64 = (const uint64_t*)Qr;
            #pragma unroll
            for (int r = 0; r < 4; ++r) {
                int b = m0 + lq * 4 + r, j = js * 16 + lm;
                size_t base = ((size_t)b * H_ + j) * 2;
                union { uint64_t u; float f[2]; } p0, p1;
                p0.u = aload64(Qr64 + base);
                p1.u = aload64(Qr64 + base + 1);
                acc[0][r] = p0.f[0]; acc[1][r] = p0.f[1];
                acc[2][r] = p1.f[0]; acc[3][r] = p1.f[1];
            }
            gemm_k1024((const uint64_t*)h2p, ws, lm, lq, m0, acc);
            #pragma unroll
            for (int r = 0; r < 4; ++r) {
                int b = m0 + lq * 4 + r, j = js * 16 + lm;
                if (t < q[r]) {
                    float iv = sigm(acc[0][r]);
                    float fv = sigm(acc[1][r]);
                    float gv = tanhf(acc[2][r]);
                    float ov = sigm(acc[3][r]);
                    float cn = fv * c_reg[r] + iv * gv;
                    float hv = ov * tanhf(cn);
                    c_reg[r] = cn; h_reg[r] = hv;
                    hb_reg[r] = f2bf(hv);
                }
                astore16(&h2n[b * H_ + j], hb_reg[r]);
            }
        }

        if (s < NSS - 1) {
            __syncthreads();   // drains vmcnt(0): all sc1 data stores complete device-wide
            if (threadIdx.x == 0) {
                int* flag = &ctr[s * 32];
                __hip_atomic_fetch_add(flag, 1, __ATOMIC_RELAXED, __HIP_MEMORY_SCOPE_AGENT);
                while (__hip_atomic_load(flag, __ATOMIC_RELAXED, __HIP_MEMORY_SCOPE_AGENT) < NBLK)
                    __builtin_amdgcn_s_sleep(1);
            }
            __syncthreads();
        }
    }

    // final states from registers (plain stores; next dispatch sees them via
    // runtime's inter-dispatch coherence)
    #pragma unroll
    for (int r = 0; r < 4; ++r) {
        int b = m0 + lq * 4 + r, j = js * 16 + lm;
        if (role == 0) { h1f[b * H_ + j] = h_reg[r]; c1f[b * H_ + j] = c_reg[r]; }
        if (role == 2) { h2f[b * H_ + j] = h_reg[r]; c2f[b * H_ + j] = c_reg[r]; }
    }
}

// ---------------- output fan-out ----------------
__global__ void write_out(const float* __restrict__ h1f, const float* __restrict__ h2f,
                          const float* __restrict__ c1f, const float* __restrict__ c2f,
                          float* __restrict__ out) {
    const long long EQ = (long long)B_ * H_ * 784;      // 51,380,224
    const long long n4 = (EQ + 4LL * B_ * H_) / 4;      // 12,910,592
    long long i4 = (long long)blockIdx.x * blockDim.x + threadIdx.x;
    long long stride = (long long)gridDim.x * blockDim.x;
    for (; i4 < n4; i4 += stride) {
        long long f = i4 * 4;
        float4 v;
        if (f < EQ) {
            long long bh = f / 784;
            float val = h2f[bh];
            v = make_float4(val, val, val, val);
        } else {
            long long r = f - EQ;
            int which = (int)(r >> 16);
            int j = (int)(r & 65535);
            const float* src = (which == 0) ? h1f : (which == 1) ? h2f : (which == 2) ? c1f : c2f;
            v = *reinterpret_cast<const float4*>(src + j);
        }
        reinterpret_cast<float4*>(out)[i4] = v;
    }
}

// ---------------- launch ----------------
extern "C" void kernel_launch(void* const* d_in, const int* in_sizes, int n_in,
                              void* d_out, int out_size, void* d_ws, size_t ws_size,
                              hipStream_t stream) {
    const int*   questions = (const int*)d_in[0];
    const int*   qlen      = (const int*)d_in[1];
    const float* embed     = (const float*)d_in[2];
    const float* W_ih1     = (const float*)d_in[3];
    const float* W_hh1     = (const float*)d_in[4];
    const float* b_ih1     = (const float*)d_in[5];
    const float* b_hh1     = (const float*)d_in[6];
    const float* W_ih2     = (const float*)d_in[7];
    const float* W_hh2     = (const float*)d_in[8];
    const float* b_ih2     = (const float*)d_in[9];
    const float* b_hh2     = (const float*)d_in[10];
    float* out = (float*)d_out;

    char* w = (char*)d_ws;
    float*    xg    = (float*)(w + 0);                 // 33,554,432
    ushort_t* Wih1p = (ushort_t*)(w + 33554432);       //  2,621,440
    ushort_t* Xp    = (ushort_t*)(w + 36175872);       //  1,310,720
    float*    Qb0   = (float*)(w + 37486592);          //  1,048,576
    float*    Qb1   = (float*)(w + 38535168);          //  1,048,576
    float*    h1f   = (float*)(w + 39583744);          //    262,144
    float*    c1f   = (float*)(w + 39845888);
    float*    h2f   = (float*)(w + 40108032);
    float*    c2f   = (float*)(w + 40370176);
    ushort_t* h1b0  = (ushort_t*)(w + 40632320);       //    131,072
    ushort_t* h1b1  = (ushort_t*)(w + 40763392);
    ushort_t* h2b0  = (ushort_t*)(w + 40894464);
    ushort_t* h2b1  = (ushort_t*)(w + 41025536);
    int*      ctr   = (int*)(w + 41156608);            // 34*32 ints = 4,352 B (end 41,160,960)

    // zero h double-buffers + barrier counters (contiguous region)
    hipMemsetAsync(w + 40632320, 0, 4 * 131072 + 34 * 32 * 4, stream);

    gather_embed<<<1280, 256, 0, stream>>>(questions, embed, Xp);
    pad_convert_wih1<<<2048, 256, 0, stream>>>(W_ih1, Wih1p);
    xgemm<<<dim3(32, 64), 256, 0, stream>>>(Xp, Wih1p, b_ih1, b_hh1, xg);

    lstm_persist<<<NBLK, 256, 0, stream>>>(W_hh1, W_ih2, W_hh2, b_ih2, b_hh2,
                                           xg, qlen,
                                           h1b0, h1b1, h2b0, h2b1, Qb0, Qb1,
                                           h1f, c1f, h2f, c2f, ctr);

    write_out<<<4096, 256, 0, stream>>>(h1f, h2f, c1f, c2f, out);
}

// Round 4
// 693.123 us; speedup vs baseline: 3.3012x; 1.2409x over previous
//
#include <hip/hip_runtime.h>
#include <hip/hip_bf16.h>
#include <cstdint>

#define B_  64
#define T_  32
#define E_  300
#define EP  320      // padded K for the x-precompute GEMM
#define H_  1024
#define G4  4096     // 4*H
#define BH  65536    // B_*H_
#define NBLK 192     // persistent blocks: 64 L1 + 64 I2 + 64 H2
#define NSS  34      // supersteps (3-stage pipeline over 32 timesteps)

typedef __attribute__((ext_vector_type(8))) short bf16x8;
typedef __attribute__((ext_vector_type(4))) float f32x4;
typedef unsigned short ushort_t;

__device__ __forceinline__ bf16x8 load_b8(const ushort_t* p) {
    union { uint4 u; bf16x8 v; } c;
    c.u = *reinterpret_cast<const uint4*>(p);
    return c.v;
}

__device__ __forceinline__ ushort_t f2bf(float x) {
    union { float f; uint32_t u; } c; c.f = x;
    uint32_t r = c.u + 0x7fffu + ((c.u >> 16) & 1u);   // RNE
    return (ushort_t)(r >> 16);
}

__device__ __forceinline__ float sigm(float x) { return 1.0f / (1.0f + __expf(-x)); }

// agent-scope (cross-XCD write-through) stores for produced data; plain loads
// are used on the consumer side (unique buffer per timestep => no stale lines)
__device__ __forceinline__ void astore64(uint64_t* p, uint64_t v) {
    __hip_atomic_store(p, v, __ATOMIC_RELAXED, __HIP_MEMORY_SCOPE_AGENT);
}
__device__ __forceinline__ void astore16(ushort_t* p, ushort_t v) {
    __hip_atomic_store(p, v, __ATOMIC_RELAXED, __HIP_MEMORY_SCOPE_AGENT);
}
__device__ __forceinline__ uint64_t packf2(float a, float b) {
    union { float f[2]; uint64_t u; } c; c.f[0] = a; c.f[1] = b; return c.u;
}

// ---------------- prep kernels ----------------

__global__ void pad_convert_wih1(const float* __restrict__ src, ushort_t* __restrict__ dst) {
    int i = blockIdx.x * blockDim.x + threadIdx.x;
    int stride = gridDim.x * blockDim.x;
    const int n = G4 * EP;
    for (; i < n; i += stride) {
        int r = i / EP, c = i - r * EP;
        dst[i] = (c < E_) ? f2bf(src[r * E_ + c]) : (ushort_t)0;
    }
}

__global__ void gather_embed(const int* __restrict__ q, const float* __restrict__ table,
                             ushort_t* __restrict__ Xp) {
    int i = blockIdx.x * blockDim.x + threadIdx.x;
    int stride = gridDim.x * blockDim.x;
    const int n = B_ * T_ * EP;
    for (; i < n; i += stride) {
        int r = i / EP, c = i - r * EP;
        Xp[i] = (c < E_) ? f2bf(table[q[r] * E_ + c]) : (ushort_t)0;
    }
}

// ---------------- x-part precompute GEMM ----------------
// xg[t][b][4H] = Xp @ Wih1p^T + (b_ih1+b_hh1)
__launch_bounds__(256)
__global__ void xgemm(const ushort_t* __restrict__ Xp, const ushort_t* __restrict__ Wp,
                      const float* __restrict__ b_ih1, const float* __restrict__ b_hh1,
                      float* __restrict__ xg) {
    int mblk = blockIdx.x, nblk = blockIdx.y;
    int wave = threadIdx.x >> 6, lane = threadIdx.x & 63;
    int lm = lane & 15, lq = lane >> 4;
    int m0 = mblk * 64 + wave * 16;
    f32x4 acc[4];
    #pragma unroll
    for (int g = 0; g < 4; ++g) {
        int n = nblk * 64 + g * 16 + lm;
        float bv = b_ih1[n] + b_hh1[n];
        acc[g] = (f32x4){bv, bv, bv, bv};
    }
    for (int k0 = 0; k0 < EP; k0 += 32) {
        bf16x8 a = load_b8(Xp + (m0 + lm) * EP + k0 + lq * 8);
        #pragma unroll
        for (int g = 0; g < 4; ++g) {
            bf16x8 b = load_b8(Wp + (nblk * 64 + g * 16 + lm) * EP + k0 + lq * 8);
            acc[g] = __builtin_amdgcn_mfma_f32_16x16x32_bf16(a, b, acc[g], 0, 0, 0);
        }
    }
    #pragma unroll
    for (int g = 0; g < 4; ++g)
        #pragma unroll
        for (int r = 0; r < 4; ++r) {
            int m = m0 + lq * 4 + r;          // m = b*T + t
            int b = m >> 5, t = m & 31;
            int n = nblk * 64 + g * 16 + lm;
            xg[((size_t)t * B_ + b) * G4 + n] = acc[g][r];
        }
}

// ---------------- persistent recurrence kernel ----------------
// blocks 0-63: L1 (Whh1), 64-127: I2 (Wih2), 128-191: H2 (Whh2)

// plain cached loads of h (unique buffer per step), register double-buffered
__device__ __forceinline__ void gemm_k1024(const ushort_t* __restrict__ hvec,
                                           const ushort_t (*w)[1032],
                                           int lm, int lq, int m0, f32x4 acc[4]) {
    const uint4* hr = reinterpret_cast<const uint4*>(hvec + (size_t)(m0 + lm) * H_);
    uint4 buf0[8], buf1[8];
    #pragma unroll
    for (int i = 0; i < 8; ++i) buf0[i] = hr[i * 4 + lq];
    #pragma unroll
    for (int grp = 0; grp < 4; ++grp) {
        const uint4* cur = (grp & 1) ? buf1 : buf0;
        uint4*       nxt = (grp & 1) ? buf0 : buf1;
        if (grp < 3) {
            #pragma unroll
            for (int i = 0; i < 8; ++i) nxt[i] = hr[(grp + 1) * 32 + i * 4 + lq];
        }
        #pragma unroll
        for (int i = 0; i < 8; ++i) {
            int k0 = grp * 256 + i * 32;
            union { uint4 u; bf16x8 v; } a; a.u = cur[i];
            #pragma unroll
            for (int g = 0; g < 4; ++g) {
                bf16x8 bb = load_b8(&w[g * 16 + lm][k0 + lq * 8]);
                acc[g] = __builtin_amdgcn_mfma_f32_16x16x32_bf16(a.v, bb, acc[g], 0, 0, 0);
            }
        }
    }
}

__global__ __launch_bounds__(256) void lstm_persist(
    const float* __restrict__ Whh1, const float* __restrict__ Wih2,
    const float* __restrict__ Whh2,
    const float* __restrict__ b_ih2, const float* __restrict__ b_hh2,
    const float* __restrict__ xg, const int* __restrict__ qlen,
    ushort_t* __restrict__ h1hist,   // 33 slots of BH bf16; slot k = h1(k-1)
    ushort_t* __restrict__ h2hist,   // 33 slots of BH bf16; slot k = h2(k-1)
    float* __restrict__ Qhist,       // 32 slots of BH*4 fp32, gate-interleaved [b][j][4]
    float* __restrict__ h1f, float* __restrict__ c1f,
    float* __restrict__ h2f, float* __restrict__ c2f,
    int* __restrict__ ctr)
{
    __shared__ ushort_t ws[64][1032];   // 132,096 B -> 1 block/CU

    const int blk  = blockIdx.x;
    const int role = blk >> 6;          // 0=L1, 1=I2, 2=H2
    const int js   = blk & 63;
    const int wave = threadIdx.x >> 6, lane = threadIdx.x & 63;
    const int lm = lane & 15, lq = lane >> 4;
    const int m0 = wave * 16;

    // ---- stage weight slice fp32 -> bf16 into LDS (once) ----
    const float* Wsrc = (role == 0) ? Whh1 : (role == 1) ? Wih2 : Whh2;
    for (int idx = threadIdx.x; idx < 64 * 256; idx += 256) {
        int r = idx >> 8, c4 = idx & 255;
        int grow = (r >> 4) * H_ + js * 16 + (r & 15);
        float4 v = reinterpret_cast<const float4*>(Wsrc + (size_t)grow * H_)[c4];
        uint2 pk;
        pk.x = (uint32_t)f2bf(v.x) | ((uint32_t)f2bf(v.y) << 16);
        pk.y = (uint32_t)f2bf(v.z) | ((uint32_t)f2bf(v.w) << 16);
        *reinterpret_cast<uint2*>(&ws[r][c4 * 4]) = pk;
    }
    __syncthreads();

    int q[4];
    #pragma unroll
    for (int r = 0; r < 4; ++r) q[r] = qlen[m0 + lq * 4 + r];

    float bi[4] = {0, 0, 0, 0};
    if (role == 1) {
        #pragma unroll
        for (int g = 0; g < 4; ++g) {
            int n = g * H_ + js * 16 + lm;
            bi[g] = b_ih2[n] + b_hh2[n];
        }
    }

    float    c_reg[4]  = {0.f, 0.f, 0.f, 0.f};
    float    h_reg[4]  = {0.f, 0.f, 0.f, 0.f};
    ushort_t hb_reg[4] = {0, 0, 0, 0};

    for (int s = 0; s < NSS; ++s) {
        if (role == 0 && s < 32) {
            const int t = s;
            const ushort_t* hp = h1hist + (size_t)t * BH;        // h1(t-1)
            ushort_t*       hn = h1hist + (size_t)(t + 1) * BH;  // h1(t)
            f32x4 acc[4];
            #pragma unroll
            for (int g = 0; g < 4; ++g)
                #pragma unroll
                for (int r = 0; r < 4; ++r)
                    acc[g][r] = xg[((size_t)t * B_ + (m0 + lq * 4 + r)) * G4 + g * H_ + js * 16 + lm];
            gemm_k1024(hp, ws, lm, lq, m0, acc);
            #pragma unroll
            for (int r = 0; r < 4; ++r) {
                int b = m0 + lq * 4 + r, j = js * 16 + lm;
                if (t < q[r]) {
                    float iv = sigm(acc[0][r]);
                    float fv = sigm(acc[1][r]);
                    float gv = tanhf(acc[2][r]);
                    float ov = sigm(acc[3][r]);
                    float cn = fv * c_reg[r] + iv * gv;
                    float hv = ov * tanhf(cn);
                    c_reg[r] = cn; h_reg[r] = hv;
                    hb_reg[r] = f2bf(hv);
                }
                astore16(&hn[b * H_ + j], hb_reg[r]);
            }
        } else if (role == 1 && s >= 1 && s <= 32) {
            // Q(t=s-1) = Wih2 . h1(s-1) + bias2
            const ushort_t* h1p = h1hist + (size_t)s * BH;       // h1(s-1)
            uint64_t* Qw64 = (uint64_t*)(Qhist + (size_t)(s - 1) * (4 * BH));
            f32x4 acc[4];
            #pragma unroll
            for (int g = 0; g < 4; ++g) acc[g] = (f32x4){bi[g], bi[g], bi[g], bi[g]};
            gemm_k1024(h1p, ws, lm, lq, m0, acc);
            #pragma unroll
            for (int r = 0; r < 4; ++r) {
                int b = m0 + lq * 4 + r, j = js * 16 + lm;
                size_t base = ((size_t)b * H_ + j) * 2;
                astore64(Qw64 + base,     packf2(acc[0][r], acc[1][r]));
                astore64(Qw64 + base + 1, packf2(acc[2][r], acc[3][r]));
            }
        } else if (role == 2 && s >= 2) {
            const int t = s - 2;
            const ushort_t* h2p = h2hist + (size_t)t * BH;       // h2(t-1)
            ushort_t*       h2n = h2hist + (size_t)(t + 1) * BH; // h2(t)
            const uint4*    Qr  = (const uint4*)(Qhist + (size_t)t * (4 * BH));
            f32x4 acc[4];
            #pragma unroll
            for (int r = 0; r < 4; ++r) {
                int b = m0 + lq * 4 + r, j = js * 16 + lm;
                uint4 p = Qr[(size_t)b * H_ + j];
                union { uint32_t u; float f; } x0, x1, x2, x3;
                x0.u = p.x; x1.u = p.y; x2.u = p.z; x3.u = p.w;
                acc[0][r] = x0.f; acc[1][r] = x1.f;
                acc[2][r] = x2.f; acc[3][r] = x3.f;
            }
            gemm_k1024(h2p, ws, lm, lq, m0, acc);
            #pragma unroll
            for (int r = 0; r < 4; ++r) {
                int b = m0 + lq * 4 + r, j = js * 16 + lm;
                if (t < q[r]) {
                    float iv = sigm(acc[0][r]);
                    float fv = sigm(acc[1][r]);
                    float gv = tanhf(acc[2][r]);
                    float ov = sigm(acc[3][r]);
                    float cn = fv * c_reg[r] + iv * gv;
                    float hv = ov * tanhf(cn);
                    c_reg[r] = cn; h_reg[r] = hv;
                    hb_reg[r] = f2bf(hv);
                }
                astore16(&h2n[b * H_ + j], hb_reg[r]);
            }
        }

        if (s < NSS - 1) {
            __syncthreads();   // drains vmcnt(0): all sc1 stores visible at L3
            if (threadIdx.x == 0) {
                __hip_atomic_fetch_add(&ctr[(s * 4 + (blk & 3)) * 32], 1,
                                       __ATOMIC_RELAXED, __HIP_MEMORY_SCOPE_AGENT);
                int sum;
                do {
                    sum = 0;
                    #pragma unroll
                    for (int k = 0; k < 4; ++k)
                        sum += __hip_atomic_load(&ctr[(s * 4 + k) * 32],
                                                 __ATOMIC_RELAXED, __HIP_MEMORY_SCOPE_AGENT);
                    if (sum < NBLK) __builtin_amdgcn_s_sleep(1);
                } while (sum < NBLK);
            }
            __syncthreads();
        }
    }

    // final states (next dispatch sees them via inter-dispatch coherence)
    #pragma unroll
    for (int r = 0; r < 4; ++r) {
        int b = m0 + lq * 4 + r, j = js * 16 + lm;
        if (role == 0) { h1f[b * H_ + j] = h_reg[r]; c1f[b * H_ + j] = c_reg[r]; }
        if (role == 2) { h2f[b * H_ + j] = h_reg[r]; c2f[b * H_ + j] = c_reg[r]; }
    }
}

// ---------------- output fan-out ----------------
__global__ void write_out(const float* __restrict__ h1f, const float* __restrict__ h2f,
                          const float* __restrict__ c1f, const float* __restrict__ c2f,
                          float* __restrict__ out) {
    const long long EQ = (long long)B_ * H_ * 784;      // 51,380,224
    const long long n4 = (EQ + 4LL * B_ * H_) / 4;      // 12,910,592
    long long i4 = (long long)blockIdx.x * blockDim.x + threadIdx.x;
    long long stride = (long long)gridDim.x * blockDim.x;
    for (; i4 < n4; i4 += stride) {
        long long f = i4 * 4;
        float4 v;
        if (f < EQ) {
            long long bh = f / 784;
            float val = h2f[bh];
            v = make_float4(val, val, val, val);
        } else {
            long long r = f - EQ;
            int which = (int)(r >> 16);
            int j = (int)(r & 65535);
            const float* src = (which == 0) ? h1f : (which == 1) ? h2f : (which == 2) ? c1f : c2f;
            v = *reinterpret_cast<const float4*>(src + j);
        }
        reinterpret_cast<float4*>(out)[i4] = v;
    }
}

// ---------------- launch ----------------
extern "C" void kernel_launch(void* const* d_in, const int* in_sizes, int n_in,
                              void* d_out, int out_size, void* d_ws, size_t ws_size,
                              hipStream_t stream) {
    const int*   questions = (const int*)d_in[0];
    const int*   qlen      = (const int*)d_in[1];
    const float* embed     = (const float*)d_in[2];
    const float* W_ih1     = (const float*)d_in[3];
    const float* W_hh1     = (const float*)d_in[4];
    const float* b_ih1     = (const float*)d_in[5];
    const float* b_hh1     = (const float*)d_in[6];
    const float* W_ih2     = (const float*)d_in[7];
    const float* W_hh2     = (const float*)d_in[8];
    const float* b_ih2     = (const float*)d_in[9];
    const float* b_hh2     = (const float*)d_in[10];
    float* out = (float*)d_out;

    char* w = (char*)d_ws;
    float*    xg     = (float*)(w + 0);                 // 33,554,432
    ushort_t* Wih1p  = (ushort_t*)(w + 33554432);       //  2,621,440
    ushort_t* Xp     = (ushort_t*)(w + 36175872);       //  1,310,720
    ushort_t* h1hist = (ushort_t*)(w + 37486592);       // 33*131,072 = 4,325,376
    ushort_t* h2hist = (ushort_t*)(w + 41811968);       // 33*131,072 = 4,325,376
    float*    Qhist  = (float*)(w + 46137344);          // 32*1,048,576 = 33,554,432
    float*    h1f    = (float*)(w + 79691776);          //    262,144
    float*    c1f    = (float*)(w + 79953920);
    float*    h2f    = (float*)(w + 80216064);
    float*    c2f    = (float*)(w + 80478208);
    int*      ctr    = (int*)(w + 80740352);            // 34*4*32*4 = 17,408 (end 80,757,760)

    // zero initial-state slots (h1(-1), h2(-1)) and barrier counters
    hipMemsetAsync(w + 37486592, 0, 131072, stream);
    hipMemsetAsync(w + 41811968, 0, 131072, stream);
    hipMemsetAsync(w + 80740352, 0, 34 * 4 * 32 * 4, stream);

    gather_embed<<<1280, 256, 0, stream>>>(questions, embed, Xp);
    pad_convert_wih1<<<2048, 256, 0, stream>>>(W_ih1, Wih1p);
    xgemm<<<dim3(32, 64), 256, 0, stream>>>(Xp, Wih1p, b_ih1, b_hh1, xg);

    lstm_persist<<<NBLK, 256, 0, stream>>>(W_hh1, W_ih2, W_hh2, b_ih2, b_hh2,
                                           xg, qlen,
                                           h1hist, h2hist, Qhist,
                                           h1f, c1f, h2f, c2f, ctr);

    write_out<<<4096, 256, 0, stream>>>(h1f, h2f, c1f, c2f, out);
}